// Round 1
// baseline (596.951 us; speedup 1.0000x reference)
//
#include <hip/hip_runtime.h>
#include <hip/hip_bf16.h>

#define N_NODES 50000
#define N_EDGES 1600000
#define HEADS 4
#define DIM 128              // HEADS*HIDE == HEADS*OUT == 128
#define NEG_SLOPE 0.2f

__device__ __forceinline__ float leaky(float x) { return x > 0.f ? x : NEG_SLOPE * x; }

// ---------------- CSR build ----------------

__global__ void zero_kernel(int* __restrict__ p, int n) {
    int i = blockIdx.x * blockDim.x + threadIdx.x;
    if (i < n) p[i] = 0;
}

__global__ void count_kernel(const int* __restrict__ ei, int* __restrict__ deg) {
    int e = blockIdx.x * blockDim.x + threadIdx.x;
    if (e < N_EDGES) {
        int dst = ei[N_EDGES + e];
        atomicAdd(&deg[dst], 1);
    }
}

// single-block scan: each thread owns a contiguous chunk; one LDS scan total.
__global__ __launch_bounds__(1024) void scan_kernel(const int* __restrict__ deg,
                                                    int* __restrict__ off,
                                                    int* __restrict__ cur) {
    const int CHUNK = (N_NODES + 1023) / 1024;   // 49
    __shared__ int sums[1024];
    int t = threadIdx.x;
    int begin = t * CHUNK;
    int endi = begin + CHUNK; if (endi > N_NODES) endi = N_NODES;
    int s = 0;
    for (int i = begin; i < endi; ++i) s += deg[i];
    sums[t] = s;
    __syncthreads();
    for (int o = 1; o < 1024; o <<= 1) {
        int x = (t >= o) ? sums[t - o] : 0;
        __syncthreads();
        sums[t] += x;
        __syncthreads();
    }
    int excl = sums[t] - s;
    for (int i = begin; i < endi; ++i) {
        int d = deg[i];
        off[i] = excl; cur[i] = excl;
        excl += d;
    }
    if (t == 1023) off[N_NODES] = sums[1023];
}

__global__ void scatter_kernel(const int* __restrict__ ei, int* __restrict__ cur,
                               int* __restrict__ csr) {
    int e = blockIdx.x * blockDim.x + threadIdx.x;
    if (e < N_EDGES) {
        int src = ei[e];
        int dst = ei[N_EDGES + e];
        int pos = atomicAdd(&cur[dst], 1);
        csr[pos] = src;
    }
}

// ---------------- GEMM: H[n][128] = act(A[n][:]) @ W[128][128] ----------------
// 64 rows x 128 cols per block, 256 threads, micro-tile 8x4 per thread.

template <int RELU>
__global__ __launch_bounds__(256) void gemm_kernel(const float* __restrict__ A,
                                                   const float* __restrict__ W,
                                                   float* __restrict__ H, int n) {
    __shared__ float Ws[32][128];
    __shared__ float Xs[32][68];   // transposed, padded (stride 272B: 16B aligned, no bank conflict)
    int t = threadIdx.x;
    int row0 = blockIdx.x * 64;
    int cg = t & 31;               // cols 4*cg .. 4*cg+3
    int rg = t >> 5;               // rows 8*rg .. 8*rg+7
    float acc[8][4] = {};
    for (int k0 = 0; k0 < 128; k0 += 32) {
#pragma unroll
        for (int i = 0; i < 4; ++i) {          // W chunk: 32x128
            int idx = t + i * 256;             // 0..1023 float4s
            int kk = idx >> 5;
            int c4 = idx & 31;
            float4 w = ((const float4*)(W + (size_t)(k0 + kk) * 128))[c4];
            ((float4*)&Ws[kk][0])[c4] = w;
        }
#pragma unroll
        for (int i = 0; i < 2; ++i) {          // X chunk: 64 rows x 32 cols, store transposed
            int idx = t + i * 256;             // 0..511 float4s
            int r = idx >> 3;
            int k4 = idx & 7;
            int gr = row0 + r;
            float4 xv = make_float4(0.f, 0.f, 0.f, 0.f);
            if (gr < n) {
                xv = ((const float4*)(A + (size_t)gr * 128 + k0))[k4];
                if (RELU) {
                    xv.x = fmaxf(xv.x, 0.f); xv.y = fmaxf(xv.y, 0.f);
                    xv.z = fmaxf(xv.z, 0.f); xv.w = fmaxf(xv.w, 0.f);
                }
            }
            Xs[k4 * 4 + 0][r] = xv.x;
            Xs[k4 * 4 + 1][r] = xv.y;
            Xs[k4 * 4 + 2][r] = xv.z;
            Xs[k4 * 4 + 3][r] = xv.w;
        }
        __syncthreads();
#pragma unroll
        for (int kk = 0; kk < 32; ++kk) {
            float4 wv = ((const float4*)&Ws[kk][0])[cg];
            float4 x0 = ((const float4*)&Xs[kk][0])[rg * 2];
            float4 x1 = ((const float4*)&Xs[kk][0])[rg * 2 + 1];
            float xr[8] = {x0.x, x0.y, x0.z, x0.w, x1.x, x1.y, x1.z, x1.w};
#pragma unroll
            for (int i = 0; i < 8; ++i) {
                acc[i][0] += xr[i] * wv.x;
                acc[i][1] += xr[i] * wv.y;
                acc[i][2] += xr[i] * wv.z;
                acc[i][3] += xr[i] * wv.w;
            }
        }
        __syncthreads();
    }
#pragma unroll
    for (int i = 0; i < 8; ++i) {
        int gr = row0 + rg * 8 + i;
        if (gr < n) {
            float4 o = make_float4(acc[i][0], acc[i][1], acc[i][2], acc[i][3]);
            ((float4*)(H + (size_t)gr * 128))[cg] = o;
        }
    }
}

// ---------------- per-node attention logit halves ----------------
// alpha_s[n][h] = dot(H[n][h*32:(h+1)*32], a_src[h]); same for dst.

__global__ __launch_bounds__(128) void alpha_kernel(const float* __restrict__ H,
                                                    const float* __restrict__ asrc,
                                                    const float* __restrict__ adst,
                                                    float* __restrict__ aS,
                                                    float* __restrict__ aD) {
    int node = blockIdx.x;
    int d = threadIdx.x;
    float h = H[(size_t)node * 128 + d];
    float s = h * asrc[d];
    float q = h * adst[d];
#pragma unroll
    for (int o = 16; o > 0; o >>= 1) {
        s += __shfl_down(s, o, 32);
        q += __shfl_down(q, o, 32);
    }
    if ((d & 31) == 0) {
        aS[node * HEADS + (d >> 5)] = s;
        aD[node * HEADS + (d >> 5)] = q;
    }
}

// ---------------- pull aggregation (segment softmax + weighted sum) ----------------
// one block (128 threads) per dst node; thread = output dim; head = d>>5.
// self-loop handled implicitly. out[d] = (sum_e w_e * h[src_e][d]) / (sum_e w_e) + bias[d]

template <int ROOT>
__global__ __launch_bounds__(128) void agg_kernel(const float* __restrict__ H,
                                                  const float* __restrict__ aS,
                                                  const float* __restrict__ aD,
                                                  const int* __restrict__ off,
                                                  const int* __restrict__ csr,
                                                  const float* __restrict__ bias,
                                                  const int* __restrict__ roots,
                                                  float* __restrict__ out) {
    __shared__ int s_src[256];
    __shared__ float s_as[256 * 4];
    int t = threadIdx.x;
    int head = t >> 5;
    int n = ROOT ? roots[blockIdx.x] : (int)blockIdx.x;
    int start = off[n], end = off[n + 1];
    int deg = end - start;
    float ad_n = aD[n * HEADS + head];
    float as_self = aS[n * HEADS + head];
    float e_self = leaky(as_self + ad_n);
    float m, denom, acc;

    if (deg <= 256) {
        for (int i = t; i < deg; i += 128) {
            int s = csr[start + i];
            s_src[i] = s;
            float4 a4 = ((const float4*)aS)[s];
            ((float4*)s_as)[i] = a4;
        }
        __syncthreads();
        // pass 1: max (redundant per-thread within head group; no reduce needed)
        m = e_self;
        for (int i = 0; i < deg; ++i) {
            float asv = s_as[i * 4 + head];
            m = fmaxf(m, leaky(asv + ad_n));
        }
        // pass 2: accumulate
        float w = __expf(e_self - m);
        denom = w;
        acc = w * H[(size_t)n * 128 + t];
        for (int i = 0; i < deg; ++i) {
            float asv = s_as[i * 4 + head];
            float we = __expf(leaky(asv + ad_n) - m);
            denom += we;
            acc += we * H[(size_t)s_src[i] * 128 + t];
        }
    } else {
        // fallback: unstaged two-pass (degree > 256; statistically never at mean 32)
        m = e_self;
        for (int e = start; e < end; ++e) {
            int s = csr[e];
            m = fmaxf(m, leaky(aS[s * HEADS + head] + ad_n));
        }
        float w = __expf(e_self - m);
        denom = w;
        acc = w * H[(size_t)n * 128 + t];
        for (int e = start; e < end; ++e) {
            int s = csr[e];
            float we = __expf(leaky(aS[s * HEADS + head] + ad_n) - m);
            denom += we;
            acc += we * H[(size_t)s * 128 + t];
        }
    }
    float res = acc / denom + bias[t];
    if (ROOT) out[(size_t)blockIdx.x * 128 + t] = res;
    else      out[(size_t)n * 128 + t] = res;
}

// ---------------- launch ----------------

extern "C" void kernel_launch(void* const* d_in, const int* in_sizes, int n_in,
                              void* d_out, int out_size, void* d_ws, size_t ws_size,
                              hipStream_t stream) {
    const float* x   = (const float*)d_in[0];
    const int*   ei  = (const int*)d_in[1];
    const int*   rts = (const int*)d_in[2];
    const float* W1  = (const float*)d_in[3];
    const float* a1s = (const float*)d_in[4];
    const float* a1d = (const float*)d_in[5];
    const float* b1  = (const float*)d_in[6];
    const float* W2  = (const float*)d_in[7];
    const float* a2s = (const float*)d_in[8];
    const float* a2d = (const float*)d_in[9];
    const float* b2  = (const float*)d_in[10];
    float* out = (float*)d_out;

    char* ws = (char*)d_ws;
    size_t o = 0;
    auto alloc = [&](size_t bytes) -> void* {
        void* p = ws + o;
        o += (bytes + 255) & ~(size_t)255;
        return p;
    };
    int* deg   = (int*)alloc((size_t)N_NODES * 4);
    int* offs  = (int*)alloc((size_t)(N_NODES + 1) * 4);
    int* cur   = (int*)alloc((size_t)N_NODES * 4);
    int* csr   = (int*)alloc((size_t)N_EDGES * 4);
    float* h1  = (float*)alloc((size_t)N_NODES * 128 * 4);   // reused for h2
    float* o1  = (float*)alloc((size_t)N_NODES * 128 * 4);
    float* aS  = (float*)alloc((size_t)N_NODES * HEADS * 4); // reused layer 2
    float* aD  = (float*)alloc((size_t)N_NODES * HEADS * 4);

    // CSR build (graph is identical for both layers)
    zero_kernel<<<(N_NODES + 255) / 256, 256, 0, stream>>>(deg, N_NODES);
    count_kernel<<<(N_EDGES + 255) / 256, 256, 0, stream>>>(ei, deg);
    scan_kernel<<<1, 1024, 0, stream>>>(deg, offs, cur);
    scatter_kernel<<<(N_EDGES + 255) / 256, 256, 0, stream>>>(ei, cur, csr);

    // layer 1
    gemm_kernel<0><<<(N_NODES + 63) / 64, 256, 0, stream>>>(x, W1, h1, N_NODES);
    alpha_kernel<<<N_NODES, 128, 0, stream>>>(h1, a1s, a1d, aS, aD);
    agg_kernel<0><<<N_NODES, 128, 0, stream>>>(h1, aS, aD, offs, csr, b1, nullptr, o1);

    // layer 2 (relu fused into GEMM load; aggregation only at the 64 roots)
    gemm_kernel<1><<<(N_NODES + 63) / 64, 256, 0, stream>>>(o1, W2, h1, N_NODES);
    alpha_kernel<<<N_NODES, 128, 0, stream>>>(h1, a2s, a2d, aS, aD);
    agg_kernel<1><<<64, 128, 0, stream>>>(h1, aS, aD, offs, csr, b2, rts, out);
}

// Round 2
// 215.177 us; speedup vs baseline: 2.7742x; 2.7742x over previous
//
#include <hip/hip_runtime.h>
#include <hip/hip_bf16.h>

#define N_NODES 50000
#define N_EDGES 1600000
#define HEADS 4
#define NEG_SLOPE 0.2f
#define CAP 16384          // max |A1| = roots + their in-neighbors (actual ~2100)
#define CAPDEG 512         // max staged in-degree (actual max ~70)
#define MCSR_CAP (1 << 20) // mini-CSR capacity (actual ~69K)

__device__ __forceinline__ float leaky(float x) { return fmaxf(x, NEG_SLOPE * x); }

// ---------------- active-set construction ----------------

__global__ void mark_roots_kernel(const int* __restrict__ roots,
                                  int* __restrict__ flagR, int* __restrict__ flag1) {
    int n = roots[threadIdx.x];   // 64 threads
    flagR[n] = 1;
    flag1[n] = 1;
}

// flag1[src] = 1 for every edge whose dst is a root
__global__ void passA_kernel(const int* __restrict__ ei, const int* __restrict__ flagR,
                             int* __restrict__ flag1) {
    int i = blockIdx.x * blockDim.x + threadIdx.x;          // vec4 edge index
    if (i * 4 >= N_EDGES) return;
    int4 d4 = ((const int4*)(ei + N_EDGES))[i];
    if (flagR[d4.x]) flag1[ei[4 * i + 0]] = 1;
    if (flagR[d4.y]) flag1[ei[4 * i + 1]] = 1;
    if (flagR[d4.z]) flag1[ei[4 * i + 2]] = 1;
    if (flagR[d4.w]) flag1[ei[4 * i + 3]] = 1;
}

__global__ void compact_kernel(const int* __restrict__ flag1, int* __restrict__ cnt,
                               int* __restrict__ list, int* __restrict__ inv) {
    int i = blockIdx.x * blockDim.x + threadIdx.x;
    if (i < N_NODES && flag1[i]) {
        int p = atomicAdd(cnt, 1);
        if (p < CAP) { list[p] = i; inv[i] = p; }
    }
}

// mini in-degree for A1 destinations
__global__ void passB_kernel(const int* __restrict__ ei, const int* __restrict__ flag1,
                             const int* __restrict__ inv, int* __restrict__ mdeg) {
    int i = blockIdx.x * blockDim.x + threadIdx.x;
    if (i * 4 >= N_EDGES) return;
    int4 d4 = ((const int4*)(ei + N_EDGES))[i];
    if (flag1[d4.x]) atomicAdd(&mdeg[inv[d4.x]], 1);
    if (flag1[d4.y]) atomicAdd(&mdeg[inv[d4.y]], 1);
    if (flag1[d4.z]) atomicAdd(&mdeg[inv[d4.z]], 1);
    if (flag1[d4.w]) atomicAdd(&mdeg[inv[d4.w]], 1);
}

// single-block exclusive scan over cnt (<= CAP) entries
__global__ __launch_bounds__(1024) void mini_scan_kernel(const int* __restrict__ mdeg,
                                                         const int* __restrict__ cntp,
                                                         int* __restrict__ moff,
                                                         int* __restrict__ mcur) {
    __shared__ int sums[1024];
    int cnt = *cntp;
    int chunk = (cnt + 1023) >> 10;
    int t = threadIdx.x;
    int begin = t * chunk;
    int endi = begin + chunk; if (endi > cnt) endi = cnt;
    int s = 0;
    for (int i = begin; i < endi; ++i) s += mdeg[i];
    sums[t] = s;
    __syncthreads();
    for (int o = 1; o < 1024; o <<= 1) {
        int x = (t >= o) ? sums[t - o] : 0;
        __syncthreads();
        sums[t] += x;
        __syncthreads();
    }
    int excl = sums[t] - s;
    for (int i = begin; i < endi; ++i) {
        int d = mdeg[i];
        moff[i] = excl; mcur[i] = excl;
        excl += d;
    }
    if (t == 1023) moff[cnt] = sums[1023];
}

__global__ void passC_kernel(const int* __restrict__ ei, const int* __restrict__ flag1,
                             const int* __restrict__ inv, int* __restrict__ mcur,
                             int* __restrict__ mcsr) {
    int i = blockIdx.x * blockDim.x + threadIdx.x;
    if (i * 4 >= N_EDGES) return;
    int4 d4 = ((const int4*)(ei + N_EDGES))[i];
    if (flag1[d4.x]) { int p = atomicAdd(&mcur[inv[d4.x]], 1); mcsr[p] = ei[4 * i + 0]; }
    if (flag1[d4.y]) { int p = atomicAdd(&mcur[inv[d4.y]], 1); mcsr[p] = ei[4 * i + 1]; }
    if (flag1[d4.z]) { int p = atomicAdd(&mcur[inv[d4.z]], 1); mcsr[p] = ei[4 * i + 2]; }
    if (flag1[d4.w]) { int p = atomicAdd(&mcur[inv[d4.w]], 1); mcsr[p] = ei[4 * i + 3]; }
}

// ---------------- GEMM + fused alpha epilogue ----------------
// H[r][128] = act(A[r][:]) @ W[128][128];  aS[r][h] = dot(H[r][h*32:], asrc[h*32:])
// 64 rows x 128 cols per block, 256 threads, 8x4 micro-tile.

template <int RELU, int DYN>
__global__ __launch_bounds__(256) void gemm_kernel(const float* __restrict__ A,
                                                   const float* __restrict__ W,
                                                   const float* __restrict__ asrc,
                                                   const float* __restrict__ adst,
                                                   float* __restrict__ H,
                                                   float* __restrict__ aS,
                                                   float* __restrict__ aD,
                                                   int n_static, const int* __restrict__ cntp) {
    __shared__ float Ws[32][128];
    __shared__ float Xs[32][68];
    int n = DYN ? *cntp : n_static;
    int ntiles = (n + 63) >> 6;
    int t = threadIdx.x;
    int cg = t & 31;
    int rg = t >> 5;
    for (int tile = blockIdx.x; tile < ntiles; tile += gridDim.x) {
        int row0 = tile * 64;
        float acc[8][4] = {};
        for (int k0 = 0; k0 < 128; k0 += 32) {
#pragma unroll
            for (int i = 0; i < 4; ++i) {          // W chunk 32x128
                int idx = t + i * 256;
                int kk = idx >> 5;
                int c4 = idx & 31;
                float4 w = ((const float4*)(W + (size_t)(k0 + kk) * 128))[c4];
                ((float4*)&Ws[kk][0])[c4] = w;
            }
#pragma unroll
            for (int i = 0; i < 2; ++i) {          // X chunk 64x32 transposed
                int idx = t + i * 256;
                int r = idx >> 3;
                int k4 = idx & 7;
                int gr = row0 + r;
                float4 xv = make_float4(0.f, 0.f, 0.f, 0.f);
                if (gr < n) {
                    xv = ((const float4*)(A + (size_t)gr * 128 + k0))[k4];
                    if (RELU) {
                        xv.x = fmaxf(xv.x, 0.f); xv.y = fmaxf(xv.y, 0.f);
                        xv.z = fmaxf(xv.z, 0.f); xv.w = fmaxf(xv.w, 0.f);
                    }
                }
                Xs[k4 * 4 + 0][r] = xv.x;
                Xs[k4 * 4 + 1][r] = xv.y;
                Xs[k4 * 4 + 2][r] = xv.z;
                Xs[k4 * 4 + 3][r] = xv.w;
            }
            __syncthreads();
#pragma unroll
            for (int kk = 0; kk < 32; ++kk) {
                float4 wv = ((const float4*)&Ws[kk][0])[cg];
                float4 x0 = ((const float4*)&Xs[kk][0])[rg * 2];
                float4 x1 = ((const float4*)&Xs[kk][0])[rg * 2 + 1];
                float xr[8] = {x0.x, x0.y, x0.z, x0.w, x1.x, x1.y, x1.z, x1.w};
#pragma unroll
                for (int i = 0; i < 8; ++i) {
                    acc[i][0] += xr[i] * wv.x;
                    acc[i][1] += xr[i] * wv.y;
                    acc[i][2] += xr[i] * wv.z;
                    acc[i][3] += xr[i] * wv.w;
                }
            }
            __syncthreads();
        }
        // store H + fused alpha (reduce over the 8 col-threads per head)
        float4 av = ((const float4*)asrc)[cg];
        float4 dv = ((const float4*)adst)[cg];
#pragma unroll
        for (int i = 0; i < 8; ++i) {
            int gr = row0 + rg * 8 + i;
            float ps = acc[i][0] * av.x + acc[i][1] * av.y + acc[i][2] * av.z + acc[i][3] * av.w;
            float pd = acc[i][0] * dv.x + acc[i][1] * dv.y + acc[i][2] * dv.z + acc[i][3] * dv.w;
            ps += __shfl_xor(ps, 1); ps += __shfl_xor(ps, 2); ps += __shfl_xor(ps, 4);
            pd += __shfl_xor(pd, 1); pd += __shfl_xor(pd, 2); pd += __shfl_xor(pd, 4);
            if (gr < n) {
                ((float4*)(H + (size_t)gr * 128))[cg] =
                    make_float4(acc[i][0], acc[i][1], acc[i][2], acc[i][3]);
                if ((cg & 7) == 0) {
                    int h = cg >> 3;
                    aS[gr * HEADS + h] = ps;
                    aD[gr * HEADS + h] = pd;
                }
            }
        }
    }
}

// ---------------- pull aggregation ----------------
// MODE 0: layer-1 — grid-stride over compact list, out compact.
// MODE 1: layer-2 — one block per root slot, rows indexed via inv.

template <int MODE>
__global__ __launch_bounds__(128) void agg_kernel(const float* __restrict__ H,
                                                  const float* __restrict__ aS,
                                                  const float* __restrict__ aD,
                                                  const int* __restrict__ moff,
                                                  const int* __restrict__ mcsr,
                                                  const float* __restrict__ bias,
                                                  const int* __restrict__ list,
                                                  const int* __restrict__ inv,
                                                  const int* __restrict__ cntp,
                                                  float* __restrict__ out) {
    __shared__ int s_src[CAPDEG];
    __shared__ float s_as[CAPDEG * 4];
    __shared__ float s_w[4][CAPDEG];
    int t = threadIdx.x;
    int head = t >> 5;
    int jl = t & 31;
    int cnt = MODE ? 64 : *cntp;
    float bval = bias[t];
    for (int j = blockIdx.x; j < cnt; j += gridDim.x) {
        int n = list[j];
        int row = MODE ? inv[n] : j;     // mini-CSR row
        int own = MODE ? row : n;        // row index into H/aS/aD
        int start = moff[row];
        int deg = moff[row + 1] - start;
        float ad_n = aD[own * HEADS + head];
        float as_self = aS[own * HEADS + head];
        float e_self = leaky(as_self + ad_n);
        float denom, acc;

        if (deg <= CAPDEG) {
            for (int i = t; i < deg; i += 128) {
                int s = mcsr[start + i];
                int si = MODE ? inv[s] : s;
                s_src[i] = si;
                ((float4*)s_as)[i] = ((const float4*)aS)[si];
            }
            __syncthreads();
            // parallel weight phase: one exp per (edge, head)
            float lm = e_self;
            for (int i = jl; i < deg; i += 32)
                lm = fmaxf(lm, leaky(s_as[i * 4 + head] + ad_n));
#pragma unroll
            for (int msk = 16; msk > 0; msk >>= 1)
                lm = fmaxf(lm, __shfl_xor(lm, msk, 32));
            float lsum = 0.f;
            for (int i = jl; i < deg; i += 32) {
                float w = __expf(leaky(s_as[i * 4 + head] + ad_n) - lm);
                s_w[head][i] = w;
                lsum += w;
            }
#pragma unroll
            for (int msk = 16; msk > 0; msk >>= 1)
                lsum += __shfl_xor(lsum, msk, 32);
            float w_self = __expf(e_self - lm);
            denom = lsum + w_self;
            __syncthreads();
            // accumulate phase: LDS-broadcast weights, gathered H rows
            acc = w_self * H[(size_t)own * 128 + t];
            for (int i = 0; i < deg; ++i)
                acc += s_w[head][i] * H[(size_t)s_src[i] * 128 + t];
        } else {
            // unstaged fallback (never expected at deg<=512)
            float m = e_self;
            for (int e = start; e < start + deg; ++e) {
                int s = mcsr[e];
                int si = MODE ? inv[s] : s;
                m = fmaxf(m, leaky(aS[si * HEADS + head] + ad_n));
            }
            float w_self = __expf(e_self - m);
            denom = w_self;
            acc = w_self * H[(size_t)own * 128 + t];
            for (int e = start; e < start + deg; ++e) {
                int s = mcsr[e];
                int si = MODE ? inv[s] : s;
                float w = __expf(leaky(aS[si * HEADS + head] + ad_n) - m);
                denom += w;
                acc += w * H[(size_t)si * 128 + t];
            }
        }
        out[(size_t)j * 128 + t] = acc / denom + bval;
        __syncthreads();   // protect LDS before next grid-stride iteration
    }
}

// ---------------- launch ----------------

extern "C" void kernel_launch(void* const* d_in, const int* in_sizes, int n_in,
                              void* d_out, int out_size, void* d_ws, size_t ws_size,
                              hipStream_t stream) {
    const float* x   = (const float*)d_in[0];
    const int*   ei  = (const int*)d_in[1];
    const int*   rts = (const int*)d_in[2];
    const float* W1  = (const float*)d_in[3];
    const float* a1s = (const float*)d_in[4];
    const float* a1d = (const float*)d_in[5];
    const float* b1  = (const float*)d_in[6];
    const float* W2  = (const float*)d_in[7];
    const float* a2s = (const float*)d_in[8];
    const float* a2d = (const float*)d_in[9];
    const float* b2  = (const float*)d_in[10];
    float* out = (float*)d_out;

    char* ws = (char*)d_ws;
    size_t o = 0;
    auto alloc = [&](size_t bytes) -> void* {
        void* p = ws + o;
        o += (bytes + 255) & ~(size_t)255;
        return p;
    };
    // zero-region (single memset): flagR | flag1 | cnt | mdeg
    int* flagR = (int*)alloc((size_t)N_NODES * 4);
    int* flag1 = (int*)alloc((size_t)N_NODES * 4);
    int* cnt   = (int*)alloc(4);
    int* mdeg  = (int*)alloc((size_t)CAP * 4);
    size_t zlen = o;   // everything from ws start
    int* list  = (int*)alloc((size_t)CAP * 4);
    int* inv   = (int*)alloc((size_t)N_NODES * 4);
    int* moff  = (int*)alloc((size_t)(CAP + 1) * 4);
    int* mcur  = (int*)alloc((size_t)CAP * 4);
    int* mcsr  = (int*)alloc((size_t)MCSR_CAP * 4);
    float* h1  = (float*)alloc((size_t)N_NODES * 128 * 4);
    float* aS1 = (float*)alloc((size_t)N_NODES * HEADS * 4);
    float* aD1 = (float*)alloc((size_t)N_NODES * HEADS * 4);
    float* o1c = (float*)alloc((size_t)CAP * 128 * 4);
    float* h2c = (float*)alloc((size_t)CAP * 128 * 4);
    float* aS2 = (float*)alloc((size_t)CAP * HEADS * 4);
    float* aD2 = (float*)alloc((size_t)CAP * HEADS * 4);

    hipMemsetAsync(ws, 0, zlen, stream);

    const int EB = (N_EDGES / 4 + 255) / 256;   // vec4 edge-pass blocks

    // active-set + mini-CSR
    mark_roots_kernel<<<1, 64, 0, stream>>>(rts, flagR, flag1);
    passA_kernel<<<EB, 256, 0, stream>>>(ei, flagR, flag1);
    compact_kernel<<<(N_NODES + 255) / 256, 256, 0, stream>>>(flag1, cnt, list, inv);
    passB_kernel<<<EB, 256, 0, stream>>>(ei, flag1, inv, mdeg);
    mini_scan_kernel<<<1, 1024, 0, stream>>>(mdeg, cnt, moff, mcur);
    passC_kernel<<<EB, 256, 0, stream>>>(ei, flag1, inv, mcur, mcsr);

    // layer 1: full-graph GEMM (+alpha fused), aggregation only at A1
    gemm_kernel<0, 0><<<(N_NODES + 63) / 64, 256, 0, stream>>>(
        x, W1, a1s, a1d, h1, aS1, aD1, N_NODES, nullptr);
    agg_kernel<0><<<2048, 128, 0, stream>>>(h1, aS1, aD1, moff, mcsr, b1, list, inv, cnt, o1c);

    // layer 2: compact GEMM (+relu on load, +alpha fused), aggregation at roots
    gemm_kernel<1, 1><<<256, 256, 0, stream>>>(
        o1c, W2, a2s, a2d, h2c, aS2, aD2, 0, cnt);
    agg_kernel<1><<<64, 128, 0, stream>>>(h2c, aS2, aD2, moff, mcsr, b2, rts, inv, cnt, out);
}